// Round 9
// baseline (376.490 us; speedup 1.0000x reference)
//
#include <hip/hip_runtime.h>
#include <hip/hip_bf16.h>
#include <stdint.h>

#define NN 4096
#define MAXNZ 1536   // cap on nnz per row of a2 (expected ~270); /4 = 384 chunks

// CSR entry format: (val << 20) | (col << 2).

// ---------------------------------------------------------------------------
// K1: scan_k — one coalesced pass over adj per row. Produces:
//   nbr (sorted neighbor list), deg, packed bit-adjacency abits (2 MB),
//   degree feats (cols 12..14). One wave per row.
// ---------------------------------------------------------------------------
__global__ __launch_bounds__(256) void scan_k(const float* __restrict__ adj,
                                              int* __restrict__ nbr,
                                              int* __restrict__ deg,
                                              unsigned long long* __restrict__ abits,
                                              float* __restrict__ feats) {
    __shared__ int nlist[4][64];
    int tid = threadIdx.x;
    int wv = tid >> 6, ln = tid & 63;
    int v = blockIdx.x * 4 + wv;
    size_t rb = (size_t)v * NN;
    int total = 0;
    unsigned long long myword = 0ull;
    for (int base = 0; base < NN; base += 64) {
        float val = adj[rb + base + ln];
        bool p = val > 0.5f;
        unsigned long long m = __ballot(p);
        if ((base >> 6) == ln) myword = m;
        if (p) {
            int pos = total + __popcll(m & ((1ull << ln) - 1ull));
            if (pos < 64) nlist[wv][pos] = base + ln;
        }
        total += __popcll(m);
    }
    abits[(size_t)v * 64 + ln] = myword;     // coalesced 8B/lane store
    int degL = min(total, 64);
    if (ln < degL) nbr[v * 64 + ln] = nlist[wv][ln];
    if (ln == 0) {
        deg[v] = total;
        float degf = (float)total;
        feats[v * 16 + 12] = degf;
        feats[v * 16 + 13] = degf * degf;
        feats[v * 16 + 14] = degf;           // diag(A^2) = deg (symmetric 0/1)
    }
}

// ---------------------------------------------------------------------------
// K2: cr_k — cr_feat (cols 0..3) from the L2-resident bitmask. One wave/node.
// ---------------------------------------------------------------------------
__global__ __launch_bounds__(256) void cr_k(const unsigned long long* __restrict__ abits,
                                            const int* __restrict__ nbr,
                                            const int* __restrict__ deg,
                                            float* __restrict__ feats) {
    __shared__ unsigned long long rows[4][64];
    __shared__ int mems[4][64];
    int tid = threadIdx.x;
    int wv = tid >> 6, ln = tid & 63;
    int v = blockIdx.x * 4 + wv;

    int dv = deg[v];
    int degL = min(dv, 64);
    int c = min(dv + 1, 64);

    int nl = (ln < degL) ? nbr[v * 64 + ln] : 0;
    int isless = (ln < degL && nl < v) ? 1 : 0;
    int pos = isless;
    #pragma unroll
    for (int off = 32; off; off >>= 1) pos += __shfl_xor(pos, off, 64);

    int mem = 0;
    if (ln < c) {
        if (ln < pos)       mem = nl;
        else if (ln == pos) mem = v;
        else                mem = nbr[v * 64 + ln - 1];
    }
    mems[wv][ln] = mem;
    __syncthreads();

    // probe bitmask rows: lane ln builds adjacency of mem_ln vs all members
    unsigned long long mask = 0ull;
    {
        const unsigned long long* rowb = abits + (size_t)mem * 64;
        for (int j = 0; j < c; j++) {
            int mj = mems[wv][j];
            unsigned long long w = rowb[mj >> 6];
            mask |= ((w >> (mj & 63)) & 1ull) << j;
        }
    }
    if (ln >= c) mask = 0ull;
    rows[wv][ln] = mask;
    __syncthreads();

    int tpart = 0;
    float epart = 0.f, wpart = 0.f;
    if (ln < c) {
        unsigned long long mm = mask;
        while (mm) {
            int j = __ffsll(mm) - 1;
            mm &= mm - 1;
            tpart += __popcll(mask & rows[wv][j]);
        }
        if (ln != pos) {
            int cn = __popcll(rows[wv][pos] & mask);
            float D = (float)cn + 1.0f;
            epart = D;
            wpart = D * (D - 1.0f) * 0.5f;
        }
    }
    float es = epart, wsum = wpart;
    int ts = tpart;
    #pragma unroll
    for (int off = 32; off; off >>= 1) {
        es += __shfl_xor(es, off, 64);
        wsum += __shfl_xor(wsum, off, 64);
        ts += __shfl_xor(ts, off, 64);
    }

    if (ln == 0) {
        float degf = (float)dv;
        float k = degf + 1.0f;
        float E = 0.5f * (es + degf);
        float W = wsum + degf * (degf - 1.0f) * 0.5f;
        float T = (float)ts / 6.0f;
        float f3 = T;
        float f2 = W - 3.0f * T;
        float f1 = E * (k - 2.0f) - 2.0f * f2 - 3.0f * f3;
        float tot = k * (k - 1.0f) * (k - 2.0f) / 6.0f;
        float f0 = tot - f1 - f2 - f3;
        if (k < 3.0f) { f0 = f1 = f2 = f3 = 0.f; }
        float s = f0 + f1 + f2 + f3 + 1e-10f;
        feats[v * 16 + 0] = f0 / s;
        feats[v * 16 + 1] = f1 / s;
        feats[v * 16 + 2] = f2 / s;
        feats[v * 16 + 3] = f3 / s;
    }
}

// ---------------------------------------------------------------------------
// K3: a2 = adj @ adj -> packed CSR ((val<<20)|(col<<2)). All-256-lane
// per-element scatter with LDS-staged u-list + degrees (1 global load per
// element, coalesced in 64-lane groups). Rows padded to x4 (val=0,
// distinct cols).
// ---------------------------------------------------------------------------
__global__ __launch_bounds__(256) void a2_k(const int* __restrict__ nbr,
                                            const int* __restrict__ deg,
                                            unsigned int* __restrict__ csr,
                                            int* __restrict__ cnt) {
    __shared__ unsigned int acc[NN];
    __shared__ int us[64];
    __shared__ int dus[64];
    __shared__ unsigned int base_s;
    int tid = threadIdx.x;
    int v = blockIdx.x;
    for (int j = tid; j < NN; j += 256) acc[j] = 0u;
    if (tid == 0) base_s = 0u;
    int dv = min(deg[v], 64);
    if (tid < dv) {
        int u = nbr[v * 64 + tid];
        us[tid] = u;
        dus[tid] = min(deg[u], 64);
    }
    __syncthreads();
    for (int p = tid; p < dv * 64; p += 256) {
        int i = p >> 6, wi = p & 63;
        int u = us[i];
        if (wi < dus[i]) atomicAdd(&acc[nbr[u * 64 + wi]], 1u);
    }
    __syncthreads();
    int j0 = tid * 16;
    unsigned int local = 0;
    #pragma unroll
    for (int m = 0; m < 16; m++) local += (acc[j0 + m] != 0u);
    unsigned int pos = atomicAdd(&base_s, local);
    unsigned int* dst = csr + (size_t)v * MAXNZ;
    #pragma unroll
    for (int m = 0; m < 16; m++) {
        unsigned int a = acc[j0 + m];
        if (a) {
            if (pos < MAXNZ) dst[pos] = (a << 20) | ((unsigned int)(j0 + m) << 2);
            pos++;
        }
    }
    __syncthreads();
    unsigned int bs = min(base_s, (unsigned int)MAXNZ);
    unsigned int padto = (bs + 3u) & ~3u;
    if (tid < padto - bs) dst[bs + tid] = (bs + tid) << 2;   // val=0, distinct col
    if (tid == 0) cnt[v] = (int)bs;
}

// ---------------------------------------------------------------------------
// K4: fused sparse a4-row + top-8 + embedding. 512 threads (8 waves)/row.
// 4-way entry fusion: cumulative chunk offsets + pre-biased packed select
// words -> inner pass is a 3-deep cndmask chain + one u32 flat index.
// ---------------------------------------------------------------------------
__device__ __forceinline__ void do4(unsigned int* acc, uint4 E, unsigned int W) {
    atomicAdd(&acc[(E.x >> 2) & 0xFFFu], W * (E.x >> 20));
    atomicAdd(&acc[(E.y >> 2) & 0xFFFu], W * (E.y >> 20));
    atomicAdd(&acc[(E.z >> 2) & 0xFFFu], W * (E.z >> 20));
    atomicAdd(&acc[(E.w >> 2) & 0xFFFu], W * (E.w >> 20));
}

__global__ __launch_bounds__(512) void a4row_k(const unsigned int* __restrict__ csr,
                                               const int* __restrict__ cnt,
                                               const float* __restrict__ feats,
                                               const float* __restrict__ e_w,
                                               const float* __restrict__ e_b,
                                               float* __restrict__ x0) {
    __shared__ unsigned int acc[NN];          // 16 KB, LDS offset 0
    __shared__ unsigned int rowe[MAXNZ];      // 6 KB
    __shared__ unsigned int wmax[8];
    __shared__ float maxs[8];
    __shared__ int winner;
    int tid = threadIdx.x;
    int wv = tid >> 6, ln = tid & 63;
    int v = blockIdx.x;

    for (int j = tid; j < NN; j += 512) acc[j] = 0u;

    int nv = cnt[v];
    int nvp = (nv + 3) & ~3;
    const unsigned int* rowv = csr + (size_t)v * MAXNZ;
    for (int i = tid; i < nvp; i += 512) {
        unsigned int e = rowv[i];
        unsigned int u = (e >> 2) & 0xFFFu;
        unsigned int w = e >> 20;                           // <= ~64
        unsigned int nc = ((unsigned int)cnt[u] + 3u) >> 2; // chunks <= 384
        rowe[i] = u | (w << 12) | (nc << 19);
    }
    __syncthreads();

    const uint4* csr4 = (const uint4*)csr;
    for (int i0 = wv * 4; i0 < nvp; i0 += 32) {
        uint4 q = *(const uint4*)&rowe[i0];
        int c1 = (int)(q.x >> 19);
        int c2 = c1 + (int)(q.y >> 19);
        int c3 = c2 + (int)(q.z >> 19);
        int tot = c3 + (int)(q.w >> 19);
        unsigned int s0 = ((q.x & 0xFFFu) * 384u + 2048u)                    | (((q.x >> 12) & 0x7Fu) << 21);
        unsigned int s1 = ((q.y & 0xFFFu) * 384u + 2048u - (unsigned int)c1) | (((q.y >> 12) & 0x7Fu) << 21);
        unsigned int s2 = ((q.z & 0xFFFu) * 384u + 2048u - (unsigned int)c2) | (((q.z >> 12) & 0x7Fu) << 21);
        unsigned int s3 = ((q.w & 0xFFFu) * 384u + 2048u - (unsigned int)c3) | (((q.w >> 12) & 0x7Fu) << 21);
        for (int g = ln; g < tot; g += 64) {
            unsigned int sel = (g < c1) ? s0 : ((g < c2) ? s1 : ((g < c3) ? s2 : s3));
            uint4 E = csr4[(sel & 0x1FFFFFu) + (unsigned int)g - 2048u];
            do4(acc, E, sel >> 21);
        }
    }
    __syncthreads();

    // per-thread top-8 over 8 coalesced LDS reads
    unsigned int best[8];
    #pragma unroll
    for (int q = 0; q < 8; q++) best[q] = 0u;
    #pragma unroll
    for (int m = 0; m < 8; m++) {
        unsigned int val = acc[tid + 512 * m];
        if (val > best[7]) {
            best[7] = val;
            #pragma unroll
            for (int s = 7; s > 0; s--) {
                if (best[s] > best[s - 1]) {
                    unsigned int t = best[s - 1]; best[s - 1] = best[s]; best[s] = t;
                } else break;
            }
        }
    }

    // 8 rounds of block max-extract
    for (int r = 0; r < 8; r++) {
        unsigned int m = best[0];
        #pragma unroll
        for (int off = 32; off; off >>= 1)
            m = max(m, (unsigned int)__shfl_xor((int)m, off, 64));
        if (ln == 0) wmax[wv] = m;
        if (tid == 0) winner = 1024;
        __syncthreads();
        unsigned int M = 0u;
        #pragma unroll
        for (int q = 0; q < 8; q++) M = max(M, wmax[q]);
        if (best[0] == M) atomicMin(&winner, tid);
        __syncthreads();
        if (tid == winner) {
            #pragma unroll
            for (int s = 0; s < 7; s++) best[s] = best[s + 1];
            best[7] = 0u;
        }
        if (tid == 0) maxs[r] = (float)M;
        __syncthreads();
    }

    // fused embedding: x0[v] = feats[v] @ e_w + e_b  (cols 4..11 from maxs)
    if (tid < 64) {
        int d = tid;
        float s = e_b[d];
        s += feats[v * 16 + 0]  * e_w[0 * 64 + d];
        s += feats[v * 16 + 1]  * e_w[1 * 64 + d];
        s += feats[v * 16 + 2]  * e_w[2 * 64 + d];
        s += feats[v * 16 + 3]  * e_w[3 * 64 + d];
        #pragma unroll
        for (int j = 0; j < 8; j++) s += maxs[j] * e_w[(4 + j) * 64 + d];
        s += feats[v * 16 + 12] * e_w[12 * 64 + d];
        s += feats[v * 16 + 13] * e_w[13 * 64 + d];
        s += feats[v * 16 + 14] * e_w[14 * 64 + d];
        x0[(size_t)v * 64 + d] = s;
    }
}

// ---------------------------------------------------------------------------
// K5: one GNN layer. For li==2, emit per-block partial column sums
// (fused stage-1 of out = x.sum(0)) instead of writing x.
// ---------------------------------------------------------------------------
__global__ __launch_bounds__(256) void layer_k(const float* __restrict__ xin,
                                               float* __restrict__ xout,
                                               const float* __restrict__ w1,
                                               const float* __restrict__ b1,
                                               const float* __restrict__ w2,
                                               const float* __restrict__ b2,
                                               const float* __restrict__ eps,
                                               const int* __restrict__ nbr,
                                               const int* __restrict__ deg,
                                               float* __restrict__ partial,
                                               int li) {
    __shared__ float h[4][64], t[4][64];
    int tid = threadIdx.x;
    int wv = tid >> 6, d = tid & 63;
    int v = blockIdx.x * 4 + wv;
    float xv = xin[(size_t)v * 64 + d];
    int dv = min(deg[v], 64);
    const int* nl = nbr + v * 64;
    float agg = 0.f;
    int j = 0;
    for (; j + 4 <= dv; j += 4) {
        int n0 = nl[j], n1 = nl[j + 1], n2 = nl[j + 2], n3 = nl[j + 3];
        float a0 = xin[(size_t)n0 * 64 + d];
        float a1 = xin[(size_t)n1 * 64 + d];
        float a2v = xin[(size_t)n2 * 64 + d];
        float a3 = xin[(size_t)n3 * 64 + d];
        agg += (a0 + a1) + (a2v + a3);
    }
    for (; j < dv; j++) agg += xin[(size_t)nl[j] * 64 + d];
    float hv = (1.0f + eps[li]) * xv + agg;
    h[wv][d] = hv;
    __syncthreads();
    float s = b1[li * 64 + d];
    #pragma unroll 8
    for (int k = 0; k < 64; k++) s += h[wv][k] * w1[li * 4096 + k * 64 + d];
    s = fmaxf(s, 0.f);
    t[wv][d] = s;
    __syncthreads();
    float o = b2[li * 64 + d];
    #pragma unroll 8
    for (int k = 0; k < 64; k++) o += t[wv][k] * w2[li * 4096 + k * 64 + d];
    if (li == 2) {
        h[wv][d] = o;
        __syncthreads();
        if (wv == 0)
            partial[blockIdx.x * 64 + d] = (h[0][d] + h[1][d]) + (h[2][d] + h[3][d]);
    } else {
        xout[(size_t)v * 64 + d] = o;
    }
}

// ---------------------------------------------------------------------------
// K6: final reduce of 1024 block partials -> out[64]
// ---------------------------------------------------------------------------
__global__ __launch_bounds__(256) void final_k(const float* __restrict__ partial,
                                               float* __restrict__ out) {
    __shared__ float p[256];
    int tid = threadIdx.x;
    int d = tid & 63, g = tid >> 6;
    float s = 0.f;
    for (int b = g; b < 1024; b += 4) s += partial[b * 64 + d];
    p[tid] = s;
    __syncthreads();
    if (tid < 64) out[tid] = p[tid] + p[tid + 64] + p[tid + 128] + p[tid + 192];
}

// ---------------------------------------------------------------------------
extern "C" void kernel_launch(void* const* d_in, const int* in_sizes, int n_in,
                              void* d_out, int out_size, void* d_ws, size_t ws_size,
                              hipStream_t stream) {
    const float* adj = (const float*)d_in[0];
    const float* e_w = (const float*)d_in[1];
    const float* e_b = (const float*)d_in[2];
    const float* w1  = (const float*)d_in[3];
    const float* b1  = (const float*)d_in[4];
    const float* w2  = (const float*)d_in[5];
    const float* b2  = (const float*)d_in[6];
    const float* eps = (const float*)d_in[7];
    float* out = (float*)d_out;

    char* ws = (char*)d_ws;
    unsigned int*       csr     = (unsigned int*)(ws);                  // 24 MB
    int*                nbr     = (int*)(ws + 25165824);                // 1 MB
    int*                deg     = (int*)(ws + 26214400);                // 16 KB
    int*                cnt     = (int*)(ws + 26230784);                // 16 KB
    float*              feats   = (float*)(ws + 26247168);              // 256 KB
    float*              x0      = (float*)(ws + 26509312);              // 1 MB
    float*              x1      = (float*)(ws + 27557888);              // 1 MB
    float*              partial = (float*)(ws + 28606464);              // 256 KB
    unsigned long long* abits   = (unsigned long long*)(ws + 28868608); // 2 MB

    scan_k<<<1024, 256, 0, stream>>>(adj, nbr, deg, abits, feats);
    cr_k<<<1024, 256, 0, stream>>>(abits, nbr, deg, feats);
    a2_k<<<4096, 256, 0, stream>>>(nbr, deg, csr, cnt);
    a4row_k<<<4096, 512, 0, stream>>>(csr, cnt, feats, e_w, e_b, x0);
    layer_k<<<1024, 256, 0, stream>>>(x0, x1, w1, b1, w2, b2, eps, nbr, deg, partial, 0);
    layer_k<<<1024, 256, 0, stream>>>(x1, x0, w1, b1, w2, b2, eps, nbr, deg, partial, 1);
    layer_k<<<1024, 256, 0, stream>>>(x0, x1, w1, b1, w2, b2, eps, nbr, deg, partial, 2);
    final_k<<<1, 256, 0, stream>>>(partial, out);
}

// Round 10
// 331.393 us; speedup vs baseline: 1.1361x; 1.1361x over previous
//
#include <hip/hip_runtime.h>
#include <hip/hip_bf16.h>
#include <stdint.h>

#define NN 4096
#define MAXNZ 1536   // cap on nnz per row of a2 (expected ~270); /8 = 192 dchunks

// CSR entry format: (val << 20) | (col << 2).

// ---------------------------------------------------------------------------
// K1: scan_k — one coalesced pass over adj per row. Produces:
//   nbr (sorted neighbor list), deg, packed bit-adjacency abits (2 MB),
//   degree feats (cols 12..14). One wave per row.
// ---------------------------------------------------------------------------
__global__ __launch_bounds__(256) void scan_k(const float* __restrict__ adj,
                                              int* __restrict__ nbr,
                                              int* __restrict__ deg,
                                              unsigned long long* __restrict__ abits,
                                              float* __restrict__ feats) {
    __shared__ int nlist[4][64];
    int tid = threadIdx.x;
    int wv = tid >> 6, ln = tid & 63;
    int v = blockIdx.x * 4 + wv;
    size_t rb = (size_t)v * NN;
    int total = 0;
    unsigned long long myword = 0ull;
    for (int base = 0; base < NN; base += 64) {
        float val = adj[rb + base + ln];
        bool p = val > 0.5f;
        unsigned long long m = __ballot(p);
        if ((base >> 6) == ln) myword = m;
        if (p) {
            int pos = total + __popcll(m & ((1ull << ln) - 1ull));
            if (pos < 64) nlist[wv][pos] = base + ln;
        }
        total += __popcll(m);
    }
    abits[(size_t)v * 64 + ln] = myword;     // coalesced 8B/lane store
    int degL = min(total, 64);
    if (ln < degL) nbr[v * 64 + ln] = nlist[wv][ln];
    if (ln == 0) {
        deg[v] = total;
        float degf = (float)total;
        feats[v * 16 + 12] = degf;
        feats[v * 16 + 13] = degf * degf;
        feats[v * 16 + 14] = degf;           // diag(A^2) = deg (symmetric 0/1)
    }
}

// ---------------------------------------------------------------------------
// K2: cr_k — cr_feat (cols 0..3) from the L2-resident bitmask. One wave/node.
// ---------------------------------------------------------------------------
__global__ __launch_bounds__(256) void cr_k(const unsigned long long* __restrict__ abits,
                                            const int* __restrict__ nbr,
                                            const int* __restrict__ deg,
                                            float* __restrict__ feats) {
    __shared__ unsigned long long rows[4][64];
    __shared__ int mems[4][64];
    int tid = threadIdx.x;
    int wv = tid >> 6, ln = tid & 63;
    int v = blockIdx.x * 4 + wv;

    int dv = deg[v];
    int degL = min(dv, 64);
    int c = min(dv + 1, 64);

    int nl = (ln < degL) ? nbr[v * 64 + ln] : 0;
    int isless = (ln < degL && nl < v) ? 1 : 0;
    int pos = isless;
    #pragma unroll
    for (int off = 32; off; off >>= 1) pos += __shfl_xor(pos, off, 64);

    int mem = 0;
    if (ln < c) {
        if (ln < pos)       mem = nl;
        else if (ln == pos) mem = v;
        else                mem = nbr[v * 64 + ln - 1];
    }
    mems[wv][ln] = mem;
    __syncthreads();

    unsigned long long mask = 0ull;
    {
        const unsigned long long* rowb = abits + (size_t)mem * 64;
        for (int j = 0; j < c; j++) {
            int mj = mems[wv][j];
            unsigned long long w = rowb[mj >> 6];
            mask |= ((w >> (mj & 63)) & 1ull) << j;
        }
    }
    if (ln >= c) mask = 0ull;
    rows[wv][ln] = mask;
    __syncthreads();

    int tpart = 0;
    float epart = 0.f, wpart = 0.f;
    if (ln < c) {
        unsigned long long mm = mask;
        while (mm) {
            int j = __ffsll(mm) - 1;
            mm &= mm - 1;
            tpart += __popcll(mask & rows[wv][j]);
        }
        if (ln != pos) {
            int cn = __popcll(rows[wv][pos] & mask);
            float D = (float)cn + 1.0f;
            epart = D;
            wpart = D * (D - 1.0f) * 0.5f;
        }
    }
    float es = epart, wsum = wpart;
    int ts = tpart;
    #pragma unroll
    for (int off = 32; off; off >>= 1) {
        es += __shfl_xor(es, off, 64);
        wsum += __shfl_xor(wsum, off, 64);
        ts += __shfl_xor(ts, off, 64);
    }

    if (ln == 0) {
        float degf = (float)dv;
        float k = degf + 1.0f;
        float E = 0.5f * (es + degf);
        float W = wsum + degf * (degf - 1.0f) * 0.5f;
        float T = (float)ts / 6.0f;
        float f3 = T;
        float f2 = W - 3.0f * T;
        float f1 = E * (k - 2.0f) - 2.0f * f2 - 3.0f * f3;
        float tot = k * (k - 1.0f) * (k - 2.0f) / 6.0f;
        float f0 = tot - f1 - f2 - f3;
        if (k < 3.0f) { f0 = f1 = f2 = f3 = 0.f; }
        float s = f0 + f1 + f2 + f3 + 1e-10f;
        feats[v * 16 + 0] = f0 / s;
        feats[v * 16 + 1] = f1 / s;
        feats[v * 16 + 2] = f2 / s;
        feats[v * 16 + 3] = f3 / s;
    }
}

// ---------------------------------------------------------------------------
// K3: a2 = adj @ adj -> packed CSR ((val<<20)|(col<<2)). All-256-lane
// per-element scatter with LDS-staged u-list + degrees. Rows padded to a
// multiple of 8 entries (val=0, distinct cols) for double-chunk consumption.
// ---------------------------------------------------------------------------
__global__ __launch_bounds__(256) void a2_k(const int* __restrict__ nbr,
                                            const int* __restrict__ deg,
                                            unsigned int* __restrict__ csr,
                                            int* __restrict__ cnt) {
    __shared__ unsigned int acc[NN];
    __shared__ int us[64];
    __shared__ int dus[64];
    __shared__ unsigned int base_s;
    int tid = threadIdx.x;
    int v = blockIdx.x;
    for (int j = tid; j < NN; j += 256) acc[j] = 0u;
    if (tid == 0) base_s = 0u;
    int dv = min(deg[v], 64);
    if (tid < dv) {
        int u = nbr[v * 64 + tid];
        us[tid] = u;
        dus[tid] = min(deg[u], 64);
    }
    __syncthreads();
    for (int p = tid; p < dv * 64; p += 256) {
        int i = p >> 6, wi = p & 63;
        int u = us[i];
        if (wi < dus[i]) atomicAdd(&acc[nbr[u * 64 + wi]], 1u);
    }
    __syncthreads();
    int j0 = tid * 16;
    unsigned int local = 0;
    #pragma unroll
    for (int m = 0; m < 16; m++) local += (acc[j0 + m] != 0u);
    unsigned int pos = atomicAdd(&base_s, local);
    unsigned int* dst = csr + (size_t)v * MAXNZ;
    #pragma unroll
    for (int m = 0; m < 16; m++) {
        unsigned int a = acc[j0 + m];
        if (a) {
            if (pos < MAXNZ) dst[pos] = (a << 20) | ((unsigned int)(j0 + m) << 2);
            pos++;
        }
    }
    __syncthreads();
    unsigned int bs = min(base_s, 1528u);
    unsigned int padto = (bs + 7u) & ~7u;
    if (tid < padto - bs) dst[bs + tid] = (bs + tid) << 2;   // val=0, distinct col
    if (tid == 0) cnt[v] = (int)bs;
}

// ---------------------------------------------------------------------------
// K4: fused sparse a4-row + top-8 + embedding. 512 threads (8 waves)/row.
// DOUBLE-CHUNK passes: each lane consumes two consecutive uint4 chunks
// (8 elements) per pass — selection + index math amortize over 8 elems,
// and the second load is a fixed +16B offset. 4-way entry fusion with
// cumulative double-chunk offsets. Zero-weight pad entries get nc=0.
// ---------------------------------------------------------------------------
__device__ __forceinline__ void do4(unsigned int* acc, uint4 E, unsigned int W) {
    atomicAdd(&acc[(E.x >> 2) & 0xFFFu], W * (E.x >> 20));
    atomicAdd(&acc[(E.y >> 2) & 0xFFFu], W * (E.y >> 20));
    atomicAdd(&acc[(E.z >> 2) & 0xFFFu], W * (E.z >> 20));
    atomicAdd(&acc[(E.w >> 2) & 0xFFFu], W * (E.w >> 20));
}

__global__ __launch_bounds__(512) void a4row_k(const unsigned int* __restrict__ csr,
                                               const int* __restrict__ cnt,
                                               const float* __restrict__ feats,
                                               const float* __restrict__ e_w,
                                               const float* __restrict__ e_b,
                                               float* __restrict__ x0) {
    __shared__ unsigned int acc[NN];                       // 16 KB, LDS offset 0
    __shared__ __align__(16) unsigned int rowe[MAXNZ];     // 6 KB
    __shared__ unsigned int wmax[8];
    __shared__ float maxs[8];
    __shared__ int winner;
    int tid = threadIdx.x;
    int wv = tid >> 6, ln = tid & 63;
    int v = blockIdx.x;

    for (int j = tid; j < NN; j += 512) acc[j] = 0u;

    int nv = cnt[v];
    int nvp = (nv + 7) & ~7;
    const unsigned int* rowv = csr + (size_t)v * MAXNZ;
    for (int i = tid; i < nvp; i += 512) {
        unsigned int e = rowv[i];
        unsigned int u = (e >> 2) & 0xFFFu;
        unsigned int w = e >> 20;                            // <= ~64
        unsigned int nc = w ? (((unsigned int)cnt[u] + 7u) >> 3) : 0u; // dchunks <= 191
        rowe[i] = u | (w << 12) | (nc << 19);
    }
    __syncthreads();

    const uint4* csr4 = (const uint4*)csr;
    for (int i0 = wv * 4; i0 < nvp; i0 += 32) {
        uint4 q = *(const uint4*)&rowe[i0];
        int c1 = (int)(q.x >> 19);
        int c2 = c1 + (int)(q.y >> 19);
        int c3 = c2 + (int)(q.z >> 19);
        int tot = c3 + (int)(q.w >> 19);
        // sel = (u*192 + 1024 - c_k) | (w << 21); u*192+1024 < 2^20
        unsigned int s0 = ((q.x & 0xFFFu) * 192u + 1024u)                    | (((q.x >> 12) & 0x7Fu) << 21);
        unsigned int s1 = ((q.y & 0xFFFu) * 192u + 1024u - (unsigned int)c1) | (((q.y >> 12) & 0x7Fu) << 21);
        unsigned int s2 = ((q.z & 0xFFFu) * 192u + 1024u - (unsigned int)c2) | (((q.z >> 12) & 0x7Fu) << 21);
        unsigned int s3 = ((q.w & 0xFFFu) * 192u + 1024u - (unsigned int)c3) | (((q.w >> 12) & 0x7Fu) << 21);
        for (int g = ln; g < tot; g += 64) {
            unsigned int sel = (g < c1) ? s0 : ((g < c2) ? s1 : ((g < c3) ? s2 : s3));
            unsigned int d2 = ((sel & 0x1FFFFFu) + (unsigned int)g - 1024u) << 1;
            const uint4* p = csr4 + d2;
            uint4 E0 = p[0];
            uint4 E1 = p[1];
            unsigned int W = sel >> 21;
            do4(acc, E0, W);
            do4(acc, E1, W);
        }
    }
    __syncthreads();

    // per-thread top-8 over 8 coalesced LDS reads
    unsigned int best[8];
    #pragma unroll
    for (int q = 0; q < 8; q++) best[q] = 0u;
    #pragma unroll
    for (int m = 0; m < 8; m++) {
        unsigned int val = acc[tid + 512 * m];
        if (val > best[7]) {
            best[7] = val;
            #pragma unroll
            for (int s = 7; s > 0; s--) {
                if (best[s] > best[s - 1]) {
                    unsigned int t = best[s - 1]; best[s - 1] = best[s]; best[s] = t;
                } else break;
            }
        }
    }

    // 8 rounds of block max-extract
    for (int r = 0; r < 8; r++) {
        unsigned int m = best[0];
        #pragma unroll
        for (int off = 32; off; off >>= 1)
            m = max(m, (unsigned int)__shfl_xor((int)m, off, 64));
        if (ln == 0) wmax[wv] = m;
        if (tid == 0) winner = 1024;
        __syncthreads();
        unsigned int M = 0u;
        #pragma unroll
        for (int q = 0; q < 8; q++) M = max(M, wmax[q]);
        if (best[0] == M) atomicMin(&winner, tid);
        __syncthreads();
        if (tid == winner) {
            #pragma unroll
            for (int s = 0; s < 7; s++) best[s] = best[s + 1];
            best[7] = 0u;
        }
        if (tid == 0) maxs[r] = (float)M;
        __syncthreads();
    }

    // fused embedding: x0[v] = feats[v] @ e_w + e_b  (cols 4..11 from maxs)
    if (tid < 64) {
        int d = tid;
        float s = e_b[d];
        s += feats[v * 16 + 0]  * e_w[0 * 64 + d];
        s += feats[v * 16 + 1]  * e_w[1 * 64 + d];
        s += feats[v * 16 + 2]  * e_w[2 * 64 + d];
        s += feats[v * 16 + 3]  * e_w[3 * 64 + d];
        #pragma unroll
        for (int j = 0; j < 8; j++) s += maxs[j] * e_w[(4 + j) * 64 + d];
        s += feats[v * 16 + 12] * e_w[12 * 64 + d];
        s += feats[v * 16 + 13] * e_w[13 * 64 + d];
        s += feats[v * 16 + 14] * e_w[14 * 64 + d];
        x0[(size_t)v * 64 + d] = s;
    }
}

// ---------------------------------------------------------------------------
// K5: one GNN layer. For li==2, accumulate block column sums directly into
// out[64] via fp32 atomics (out pre-zeroed by hipMemsetAsync).
// ---------------------------------------------------------------------------
__global__ __launch_bounds__(256) void layer_k(const float* __restrict__ xin,
                                               float* __restrict__ xout,
                                               const float* __restrict__ w1,
                                               const float* __restrict__ b1,
                                               const float* __restrict__ w2,
                                               const float* __restrict__ b2,
                                               const float* __restrict__ eps,
                                               const int* __restrict__ nbr,
                                               const int* __restrict__ deg,
                                               float* __restrict__ out,
                                               int li) {
    __shared__ float h[4][64], t[4][64];
    int tid = threadIdx.x;
    int wv = tid >> 6, d = tid & 63;
    int v = blockIdx.x * 4 + wv;
    float xv = xin[(size_t)v * 64 + d];
    int dv = min(deg[v], 64);
    const int* nl = nbr + v * 64;
    float agg = 0.f;
    int j = 0;
    for (; j + 4 <= dv; j += 4) {
        int n0 = nl[j], n1 = nl[j + 1], n2 = nl[j + 2], n3 = nl[j + 3];
        float a0 = xin[(size_t)n0 * 64 + d];
        float a1 = xin[(size_t)n1 * 64 + d];
        float a2v = xin[(size_t)n2 * 64 + d];
        float a3 = xin[(size_t)n3 * 64 + d];
        agg += (a0 + a1) + (a2v + a3);
    }
    for (; j < dv; j++) agg += xin[(size_t)nl[j] * 64 + d];
    float hv = (1.0f + eps[li]) * xv + agg;
    h[wv][d] = hv;
    __syncthreads();
    float s = b1[li * 64 + d];
    #pragma unroll 8
    for (int k = 0; k < 64; k++) s += h[wv][k] * w1[li * 4096 + k * 64 + d];
    s = fmaxf(s, 0.f);
    t[wv][d] = s;
    __syncthreads();
    float o = b2[li * 64 + d];
    #pragma unroll 8
    for (int k = 0; k < 64; k++) o += t[wv][k] * w2[li * 4096 + k * 64 + d];
    if (li == 2) {
        h[wv][d] = o;
        __syncthreads();
        if (wv == 0)
            atomicAdd(&out[d], (h[0][d] + h[1][d]) + (h[2][d] + h[3][d]));
    } else {
        xout[(size_t)v * 64 + d] = o;
    }
}

// ---------------------------------------------------------------------------
extern "C" void kernel_launch(void* const* d_in, const int* in_sizes, int n_in,
                              void* d_out, int out_size, void* d_ws, size_t ws_size,
                              hipStream_t stream) {
    const float* adj = (const float*)d_in[0];
    const float* e_w = (const float*)d_in[1];
    const float* e_b = (const float*)d_in[2];
    const float* w1  = (const float*)d_in[3];
    const float* b1  = (const float*)d_in[4];
    const float* w2  = (const float*)d_in[5];
    const float* b2  = (const float*)d_in[6];
    const float* eps = (const float*)d_in[7];
    float* out = (float*)d_out;

    char* ws = (char*)d_ws;
    unsigned int*       csr     = (unsigned int*)(ws);                  // 24 MB
    int*                nbr     = (int*)(ws + 25165824);                // 1 MB
    int*                deg     = (int*)(ws + 26214400);                // 16 KB
    int*                cnt     = (int*)(ws + 26230784);                // 16 KB
    float*              feats   = (float*)(ws + 26247168);              // 256 KB
    float*              x0      = (float*)(ws + 26509312);              // 1 MB
    float*              x1      = (float*)(ws + 27557888);              // 1 MB
    unsigned long long* abits   = (unsigned long long*)(ws + 28868608); // 2 MB

    hipMemsetAsync(out, 0, 64 * sizeof(float), stream);
    scan_k<<<1024, 256, 0, stream>>>(adj, nbr, deg, abits, feats);
    cr_k<<<1024, 256, 0, stream>>>(abits, nbr, deg, feats);
    a2_k<<<4096, 256, 0, stream>>>(nbr, deg, csr, cnt);
    a4row_k<<<4096, 512, 0, stream>>>(csr, cnt, feats, e_w, e_b, x0);
    layer_k<<<1024, 256, 0, stream>>>(x0, x1, w1, b1, w2, b2, eps, nbr, deg, out, 0);
    layer_k<<<1024, 256, 0, stream>>>(x1, x0, w1, b1, w2, b2, eps, nbr, deg, out, 1);
    layer_k<<<1024, 256, 0, stream>>>(x0, x1, w1, b1, w2, b2, eps, nbr, deg, out, 2);
}